// Round 6
// baseline (142.849 us; speedup 1.0000x reference)
//
#include <hip/hip_runtime.h>

#define NR 131072
#define DD 32
#define KK 64
#define BETA_C 10.0f
#define WROWS 256                    // rows per syrk worker
#define GRIDW 640                    // >= sum ceil(c_k/WROWS) <= 512+64 = 576
#define TRI(i, j) ((i) * ((i) + 1) / 2 + (j))

// ---------------------------------------------------------------------------
// R13 = R12 with phase1 restructured (only change).
// R12 post-mortem: phase1 still ~35-40 us timed, latency-bound at the
// grid-imposed 2 waves/SIMD with a ~112-reg live set and serialized scalar
// center loads. R13 phase1: 4 lanes per row, each owning k = (lane&3) mod 4
// (16 centers) -> live set ~70 regs; block 1024 thr, launch_bounds(1024,4)
// -> 4 waves/SIMD; centers in LDS cS[64][36]: per instruction the wave hits
// only 4 distinct 16-B addrs (16-way broadcast free; stride 36 -> the 4
// addrs land on 16 consecutive banks, conflict-free). Argmin tie-break and
// dot/xx accumulation chains bit-identical to the validated kernel; the
// fill transpose-reduce is the 4-bit isomorph of the validated 6-bit one
// (final mapping: lane holds fill[k=lane], epilogue unchanged).
//
// ws layout (float-indexed), unchanged:
//   [0,64)        fill_g    [64,65) lossAcc
//   [128,192)     hist_g (int)      [192,260) segStart (int 65)
//   [320,384)     cursor (int)      [384,544) wk (uchar GRIDW)
//   [544,1184)    wbase (int)       [1184,1824) wcnt (int)
//   [1824,35616)  m2low_g (K x 528 tri)   [35616,37664) sums_g (K x 32)
//   [37664,70432) pred8 (uchar N)   [70432,+N) idx (uint N, 512 KB)
// memset zeroes [0,37664) floats; everything past is fully overwritten.
// ---------------------------------------------------------------------------

// phase 1 v2: 1024 threads = 16 waves; 4 lanes/row (quad), 16 rows/wave,
// 256 rows/block, grid = NR/256 = 512 blocks.
__global__ __launch_bounds__(1024, 4) void phase1_kernel(
    const float* __restrict__ x, const float* __restrict__ centers,
    float* __restrict__ fill_g, int* __restrict__ hist_g,
    unsigned char* __restrict__ pred_g) {
  __shared__ float cS[KK][36];      // centers tile, stride 36 (bank-spread)
  __shared__ float cnS[KK];
  __shared__ float fillW[16][KK];   // per-wave fill partials
  __shared__ int histS[KK];

  const int tid = threadIdx.x;
  const int lane = tid & 63;
  const int wid = tid >> 6;
  const int kl = lane & 3;          // k-subgroup: this lane owns k = kl + 4q
  const int r = lane >> 2;          // row-within-wave 0..15

  // stage centers into LDS (2048 floats by 1024 threads)
  {
    const int e0 = tid, e1 = tid + 1024;
    cS[e0 >> 5][e0 & 31] = centers[e0];
    cS[e1 >> 5][e1 & 31] = centers[e1];
    if (tid < KK) histS[tid] = 0;
  }
  __syncthreads();
  if (tid < KK) {
    float s = 0.f;
#pragma unroll
    for (int j = 0; j < DD; ++j) s += cS[tid][j] * cS[tid][j];
    cnS[tid] = s;  // same ascending-j chain as validated kernel
  }
  __syncthreads();

  const int row = blockIdx.x * 256 + wid * 16 + r;

  float4 xr4[8];
  const float4* xp = (const float4*)(x + (size_t)row * DD);
#pragma unroll
  for (int j = 0; j < 8; ++j) xr4[j] = xp[j];  // quad-duplicated, L1-served
  float xx = 0.f;
#pragma unroll
  for (int j = 0; j < 8; ++j)
    xx += xr4[j].x * xr4[j].x + xr4[j].y * xr4[j].y + xr4[j].z * xr4[j].z +
          xr4[j].w * xr4[j].w;  // ascending-j chain, same as before

  float pv[16];
  float best = 3.4e38f;
  int bi = 0;
#pragma unroll
  for (int q = 0; q < 16; ++q) {
    const int k = 4 * q + kl;  // ascending within lane -> strict < keeps
    const float4* cp = (const float4*)&cS[k][0];  // 144-B rows, 16-B aligned
    float dot = 0.f;
#pragma unroll
    for (int jc = 0; jc < 8; ++jc) {
      const float4 c = cp[jc];
      dot += xr4[jc].x * c.x;
      dot += xr4[jc].y * c.y;
      dot += xr4[jc].z * c.z;
      dot += xr4[jc].w * c.w;
    }
    const float d2 = xx - 2.0f * dot + cnS[k];
    pv[q] = d2;
    if (d2 < best) { best = d2; bi = k; }
  }

  // quad argmin: smallest d2, ties -> smallest k (global first-index order)
#pragma unroll
  for (int d = 1; d <= 2; d <<= 1) {
    const float ob = __shfl_xor(best, d, 64);
    const int obi = __shfl_xor(bi, d, 64);
    if (ob < best || (ob == best && obi < bi)) { best = ob; bi = obi; }
  }
  if (kl == 0) {
    pred_g[row] = (unsigned char)bi;
    atomicAdd(&histS[bi], 1);
  }

  float ssum = 0.f;
#pragma unroll
  for (int q = 0; q < 16; ++q) {
    const float e = __expf(BETA_C * (best - pv[q]));
    pv[q] = e;
    ssum += e;
  }
  ssum += __shfl_xor(ssum, 1, 64);
  ssum += __shfl_xor(ssum, 2, 64);
  const float inv = 1.0f / ssum;
#pragma unroll
  for (int q = 0; q < 16; ++q) pv[q] *= inv;

  // fill transpose-reduce over the 16 row-lanes sharing kl (lane bits 2..5):
  // 4-bit isomorph of the validated 6-bit butterfly; lands fill[k] at lane k
  // (k = kl + 4q, q = lane>>2  =>  k == lane).
#pragma unroll
  for (int m = 8; m >= 1; m >>= 1) {
    const int lm = 4 * m;  // lane-xor mask on bits 2..5
    const bool hi = (lane & lm) != 0;
#pragma unroll
    for (int i = 0; i < m; ++i) {
      const float send = hi ? pv[i] : pv[i + m];
      const float recv = __shfl_xor(send, lm, 64);
      const float keep = hi ? pv[i + m] : pv[i];
      pv[i] = keep + recv;
    }
  }
  fillW[wid][lane] = pv[0];
  __syncthreads();
  if (tid < KK) {
    float s = 0.f;
#pragma unroll
    for (int w = 0; w < 16; ++w) s += fillW[w][tid];
    atomicAdd(&fill_g[tid], s);
    if (histS[tid]) atomicAdd(&hist_g[tid], histS[tid]);
  }
}

// planner v2 (validated): 64 threads, wave-shuffle exclusive scans.
__global__ void planner_kernel(const int* __restrict__ hist_g,
                               int* __restrict__ segStart,
                               int* __restrict__ cursor,
                               unsigned char* __restrict__ wk,
                               int* __restrict__ wbase,
                               int* __restrict__ wcnt) {
  const int t = threadIdx.x;  // 64 threads, one wave
  const int c = hist_g[t];

  int inc = c;
#pragma unroll
  for (int off = 1; off < 64; off <<= 1) {
    const int v = __shfl_up(inc, off, 64);
    if (t >= off) inc += v;
  }
  const int seg = inc - c;  // exclusive
  segStart[t] = seg;
  cursor[t] = seg;
  if (t == 63) segStart[KK] = inc;  // == NR

  const int nw = (c + WROWS - 1) / WROWS;
  int winc = nw;
#pragma unroll
  for (int off = 1; off < 64; off <<= 1) {
    const int v = __shfl_up(winc, off, 64);
    if (t >= off) winc += v;
  }
  const int woff = winc - nw;
  const int wtot = __shfl(winc, 63, 64);  // total workers <= 576

  for (int wi = 0; wi < nw; ++wi) {
    wk[woff + wi] = (unsigned char)t;
    wbase[woff + wi] = seg + wi * WROWS;
    wcnt[woff + wi] = min(WROWS, c - wi * WROWS);
  }
  for (int w = wtot + t; w < GRIDW; w += 64) wk[w] = 255;
}

// scatter v2 (validated R11): counting-sort of ROW INDICES only.
__global__ __launch_bounds__(256) void scatter_kernel(
    const unsigned char* __restrict__ pred_g, int* __restrict__ cursor,
    unsigned int* __restrict__ idxg) {
  __shared__ int histS[KK];
  __shared__ int baseS[KK];

  const int tid = threadIdx.x;
  if (tid < KK) histS[tid] = 0;
  __syncthreads();

  const int row = blockIdx.x * 256 + tid;
  const int bi = pred_g[row];
  const int rank = atomicAdd(&histS[bi], 1);
  __syncthreads();
  if (tid < KK) {
    const int h = histS[tid];
    baseS[tid] = h ? atomicAdd(&cursor[tid], h) : 0;
  }
  __syncthreads();
  idxg[baseS[bi] + rank] = (unsigned int)row;  // ~4-row runs per cluster
}

// syrk v4 (validated R11): worker = (cluster k, <=256 rows via index list).
// Gather rows from x into transposed LDS tile; 4 wave-groups each compute a
// full 32x32 partial with 4x4 register tiles; LDS reduction across groups;
// lower-triangle atomic flush.
__global__ __launch_bounds__(256) void syrk_kernel(
    const float* __restrict__ x, const unsigned int* __restrict__ idxg,
    const unsigned char* __restrict__ wk, const int* __restrict__ wbase,
    const int* __restrict__ wcnt, float* __restrict__ m2low_g,
    float* __restrict__ sums_g) {
  __shared__ float xsT[DD][68];    // transposed tile, 8.7 KB (rows of 17 f4)
  __shared__ float red[4][64][16]; // per-group 4x4-tile partials, 16 KB
  __shared__ float sdred[4][DD];   // per-group row sums, 0.5 KB

  const int b = blockIdx.x;
  const int k = wk[b];
  if (k == 255) return;
  const int tid = threadIdx.x;
  const int base = wbase[b];
  const int total = wcnt[b];

  const int grp = tid >> 6;   // 4 groups == 4 waves
  const int t6 = tid & 63;
  const int ti = t6 >> 3;     // 0..7: output rows i = ti + 8r, r=0..3
  const int tj = t6 & 7;      // 0..7: output cols j = tj + 8c, c=0..3

  float cc[4][4];
#pragma unroll
  for (int r = 0; r < 4; ++r)
#pragma unroll
    for (int c2 = 0; c2 < 4; ++c2) cc[r][c2] = 0.f;
  float sd[4] = {0.f, 0.f, 0.f, 0.f};

  const float4* xf4 = (const float4*)x;
  const int rl0 = tid >> 3;       // row-local for pass 0 (0..31)
  const int pt = tid & 7;         // float4 slot within row

  for (int off = 0; off < total; off += 64) {
    const int cnt = min(64, total - off);
    const int cnt4 = (cnt + 3) & ~3;
    __syncthreads();  // previous tile's readers done before overwrite

    // gather <=64 rows from x via idx; lanes 0..7 share one row (bcast idx
    // load, 128 B coalesced row read as 2 float4 per thread-pass)
    if (rl0 < cnt) {
      const unsigned int r0 = idxg[base + off + rl0];
      const float4 v = xf4[(size_t)r0 * 8 + pt];
      xsT[pt * 4 + 0][rl0] = v.x;
      xsT[pt * 4 + 1][rl0] = v.y;
      xsT[pt * 4 + 2][rl0] = v.z;
      xsT[pt * 4 + 3][rl0] = v.w;
    }
    const int rl1 = rl0 + 32;
    if (rl1 < cnt) {
      const unsigned int r1 = idxg[base + off + rl1];
      const float4 v = xf4[(size_t)r1 * 8 + pt];
      xsT[pt * 4 + 0][rl1] = v.x;
      xsT[pt * 4 + 1][rl1] = v.y;
      xsT[pt * 4 + 2][rl1] = v.z;
      xsT[pt * 4 + 3][rl1] = v.w;
    }
    for (int e = cnt * DD + tid; e < cnt4 * DD; e += 256)
      xsT[e & 31][e >> 5] = 0.f;  // zero-pad rows to multiple of 4
    __syncthreads();

    const int gmax = cnt4 >> 2;
    for (int g = grp; g < gmax; g += 4) {  // row-quads strided by group
      float4 Af[4], Bf[4];
#pragma unroll
      for (int r = 0; r < 4; ++r)
        Af[r] = *(const float4*)&xsT[ti + 8 * r][4 * g];
#pragma unroll
      for (int c2 = 0; c2 < 4; ++c2)
        Bf[c2] = *(const float4*)&xsT[tj + 8 * c2][4 * g];
#pragma unroll
      for (int r = 0; r < 4; ++r)
#pragma unroll
        for (int c2 = 0; c2 < 4; ++c2)
          cc[r][c2] += Af[r].x * Bf[c2].x + Af[r].y * Bf[c2].y +
                       Af[r].z * Bf[c2].z + Af[r].w * Bf[c2].w;
      if (tj == 0) {
#pragma unroll
        for (int r = 0; r < 4; ++r)
          sd[r] += Af[r].x + Af[r].y + Af[r].z + Af[r].w;
      }
    }
  }

  // cross-group reduction through LDS, then triangular flush
#pragma unroll
  for (int r = 0; r < 4; ++r)
    *(float4*)&red[grp][t6][r * 4] =
        make_float4(cc[r][0], cc[r][1], cc[r][2], cc[r][3]);
  if (tj == 0) {
#pragma unroll
    for (int r = 0; r < 4; ++r) sdred[grp][ti + 8 * r] = sd[r];
  }
  __syncthreads();

  float* m2k = m2low_g + k * 528;
  {
    const int t6r = tid >> 2;        // which 4x4 tile (0..63)
    const int rr = tid & 3;          // which row of that tile
    const int tir = t6r >> 3, tjr = t6r & 7;
    const int i = tir + 8 * rr;
    float4 v0 = *(const float4*)&red[0][t6r][rr * 4];
    const float4 v1 = *(const float4*)&red[1][t6r][rr * 4];
    const float4 v2 = *(const float4*)&red[2][t6r][rr * 4];
    const float4 v3 = *(const float4*)&red[3][t6r][rr * 4];
    v0.x += v1.x + v2.x + v3.x;
    v0.y += v1.y + v2.y + v3.y;
    v0.z += v1.z + v2.z + v3.z;
    v0.w += v1.w + v2.w + v3.w;
    const float vv[4] = {v0.x, v0.y, v0.z, v0.w};
#pragma unroll
    for (int q = 0; q < 4; ++q) {
      const int j = tjr + 8 * q;
      if (j <= i) atomicAdd(&m2k[TRI(i, j)], vv[q]);
    }
  }
  if (tid < DD) {
    const float s =
        sdred[0][tid] + sdred[1][tid] + sdred[2][tid] + sdred[3][tid];
    atomicAdd(&sums_g[k * DD + tid], s);
  }
}

// finalize A (validated): one block per cluster.
__global__ __launch_bounds__(256) void finalizeA_kernel(
    const float* __restrict__ fill_g, const int* __restrict__ hist_g,
    const float* __restrict__ sums_g, const float* __restrict__ m2low_g,
    const float* __restrict__ ft, const float* __restrict__ mt,
    const float* __restrict__ ct, float* __restrict__ lossAcc) {
  __shared__ float meanS[DD];
  __shared__ float wred[4];
  const int t = threadIdx.x;
  const int k = blockIdx.x;

  const float inv = 1.0f / fmaxf((float)hist_g[k], 1.0f);
  if (t < DD) meanS[t] = sums_g[k * DD + t] * inv;
  __syncthreads();

  float acc = 0.f;
  if (t < DD) {
    const float d = meanS[t] - mt[k * DD + t];
    acc += d * d * (1.0f / (KK * DD));
  }
  if (t == 0) {
    const float f = fill_g[k] * (1.0f / (float)NR) - ft[k];
    acc += f * f * (1.0f / KK);
  }
  const float* m2k = m2low_g + k * 528;
  const float* ctk = ct + k * (DD * DD);
#pragma unroll
  for (int u = 0; u < 4; ++u) {
    const int e = t + 256 * u;
    const int i = e >> 5, j = e & 31;
    const int idx = (i >= j) ? TRI(i, j) : TRI(j, i);
    const float cov = m2k[idx] * inv - meanS[i] * meanS[j];
    const float d = cov - ctk[e];
    acc += d * d * (1.0f / (KK * DD * DD));
  }

  acc += __shfl_xor(acc, 32, 64);
  acc += __shfl_xor(acc, 16, 64);
  acc += __shfl_xor(acc, 8, 64);
  acc += __shfl_xor(acc, 4, 64);
  acc += __shfl_xor(acc, 2, 64);
  acc += __shfl_xor(acc, 1, 64);
  if ((t & 63) == 0) wred[t >> 6] = acc;
  __syncthreads();
  if (t == 0) atomicAdd(lossAcc, wred[0] + wred[1] + wred[2] + wred[3]);
}

__global__ void finalizeB_kernel(const float* __restrict__ lossAcc,
                                 float* __restrict__ out) {
  if (threadIdx.x == 0) out[0] = lossAcc[0];
}

extern "C" void kernel_launch(void* const* d_in, const int* in_sizes, int n_in,
                              void* d_out, int out_size, void* d_ws,
                              size_t ws_size, hipStream_t stream) {
  (void)in_sizes; (void)n_in; (void)out_size; (void)ws_size;
  const float* x = (const float*)d_in[0];
  const float* centers = (const float*)d_in[1];
  const float* ft = (const float*)d_in[2];
  const float* mt = (const float*)d_in[3];
  const float* ct = (const float*)d_in[4];
  float* out = (float*)d_out;

  float* ws = (float*)d_ws;
  float* fill_g = ws;                                   // 64
  float* lossAcc = ws + 64;                             // 1
  int* hist_g = (int*)(ws + 128);                       // 64
  int* segStart = (int*)(ws + 192);                     // 65
  int* cursor = (int*)(ws + 320);                       // 64
  unsigned char* wk = (unsigned char*)(ws + 384);       // GRIDW bytes
  int* wbase = (int*)(ws + 544);                        // GRIDW
  int* wcnt = (int*)(ws + 1184);                        // GRIDW
  float* m2low_g = ws + 1824;                           // 33792
  float* sums_g = ws + 35616;                           // 2048
  unsigned char* pred8 = (unsigned char*)(ws + 37664);  // N bytes
  unsigned int* idxg = (unsigned int*)(ws + 70432);     // N uints (512 KB)

  hipMemsetAsync(d_ws, 0, (size_t)37664 * sizeof(float), stream);

  phase1_kernel<<<NR / 256, 1024, 0, stream>>>(x, centers, fill_g, hist_g,
                                               pred8);
  planner_kernel<<<1, 64, 0, stream>>>(hist_g, segStart, cursor, wk, wbase,
                                       wcnt);
  scatter_kernel<<<NR / 256, 256, 0, stream>>>(pred8, cursor, idxg);
  syrk_kernel<<<GRIDW, 256, 0, stream>>>(x, idxg, wk, wbase, wcnt, m2low_g,
                                         sums_g);
  finalizeA_kernel<<<KK, 256, 0, stream>>>(fill_g, hist_g, sums_g, m2low_g, ft,
                                           mt, ct, lossAcc);
  finalizeB_kernel<<<1, 64, 0, stream>>>(lossAcc, out);
}

// Round 7
// 133.619 us; speedup vs baseline: 1.0691x; 1.0691x over previous
//
#include <hip/hip_runtime.h>

#define NR 131072
#define DD 32
#define KK 64
#define BETA_C 10.0f
#define WROWS 256                    // rows per syrk worker
#define GRIDW 640                    // >= sum ceil(c_k/WROWS) <= 512+64 = 576
#define TRI(i, j) ((i) * ((i) + 1) / 2 + (j))

// ---------------------------------------------------------------------------
// R14 = R12 with ONE change: phase1 dot loop restructured for ILP.
// R13 post-mortem: LDS-fed dots = 20 us of ds_read issue vs 4 us FMA ->
// regression; operands must stay on the s_load broadcast path. R12 residual
// stall: per-k serial 32-FMA chain (128 cyc latency) poorly interleaved ->
// VALUBusy 18%. R14: k-blocks of 4 with j-inner interleave -> 4 independent
// serial chains, dep distance 8 cyc >= 4-cyc FMA latency -> fully pipelined.
// Each dot keeps its ascending-j serial order (bit-identical); best/argmin
// updates ascend in k (first-index ties preserved). Epilogue unchanged.
//
// ws layout (float-indexed), unchanged:
//   [0,64)        fill_g    [64,65) lossAcc
//   [128,192)     hist_g (int)      [192,260) segStart (int 65)
//   [320,384)     cursor (int)      [384,544) wk (uchar GRIDW)
//   [544,1184)    wbase (int)       [1184,1824) wcnt (int)
//   [1824,35616)  m2low_g (K x 528 tri)   [35616,37664) sums_g (K x 32)
//   [37664,70432) pred8 (uchar N)   [70432,+N) idx (uint N, 512 KB)
// memset zeroes [0,37664) floats; everything past is fully overwritten.
// ---------------------------------------------------------------------------

// phase 1: one row/thread, centers via wave-uniform s_load path, 63-shuffle
// transpose-reduce for filling, per-block histogram. (256,2) bounds.
__global__ __launch_bounds__(256, 2) void phase1_kernel(
    const float* __restrict__ x, const float* __restrict__ centers,
    float* __restrict__ fill_g, int* __restrict__ hist_g,
    unsigned char* __restrict__ pred_g) {
  __shared__ float cnS[KK];
  __shared__ float fillW[4][KK];
  __shared__ int histS[KK];

  const int tid = threadIdx.x;
  const int lane = tid & 63;
  const int wid = tid >> 6;

  if (tid < KK) {
    float s = 0.f;
    const float* cp = centers + tid * DD;
#pragma unroll
    for (int j = 0; j < DD; ++j) s += cp[j] * cp[j];
    cnS[tid] = s;
    histS[tid] = 0;
  }
  __syncthreads();

  const int row = blockIdx.x * 256 + tid;  // grid == NR/256 exactly

  float xr[DD];
  const float4* xp = (const float4*)(x + (size_t)row * DD);
#pragma unroll
  for (int j = 0; j < 8; ++j) {
    const float4 v = xp[j];
    xr[4 * j + 0] = v.x;
    xr[4 * j + 1] = v.y;
    xr[4 * j + 2] = v.z;
    xr[4 * j + 3] = v.w;
  }
  float xx = 0.f;
#pragma unroll
  for (int j = 0; j < DD; ++j) xx += xr[j] * xr[j];

  float pv[KK];
  float best = 3.4e38f;
  int bi = 0;
  // k-blocks of 4: j-inner interleaves 4 independent serial dot chains
  // (each chain ascending-j, bit-identical to the validated kernel).
#pragma unroll
  for (int kb = 0; kb < KK / 4; ++kb) {
    const float* c0 = centers + (4 * kb + 0) * DD;  // uniform -> s_load (K$)
    const float* c1 = centers + (4 * kb + 1) * DD;
    const float* c2 = centers + (4 * kb + 2) * DD;
    const float* c3 = centers + (4 * kb + 3) * DD;
    float dA = 0.f, dB = 0.f, dC = 0.f, dD2 = 0.f;
#pragma unroll
    for (int j = 0; j < DD; ++j) {
      const float xj = xr[j];
      dA += xj * c0[j];
      dB += xj * c1[j];
      dC += xj * c2[j];
      dD2 += xj * c3[j];
    }
    const float e0 = xx - 2.0f * dA + cnS[4 * kb + 0];
    const float e1 = xx - 2.0f * dB + cnS[4 * kb + 1];
    const float e2 = xx - 2.0f * dC + cnS[4 * kb + 2];
    const float e3 = xx - 2.0f * dD2 + cnS[4 * kb + 3];
    pv[4 * kb + 0] = e0;
    pv[4 * kb + 1] = e1;
    pv[4 * kb + 2] = e2;
    pv[4 * kb + 3] = e3;
    // ascending-k updates, strict < == first-index ties (as validated)
    if (e0 < best) { best = e0; bi = 4 * kb + 0; }
    if (e1 < best) { best = e1; bi = 4 * kb + 1; }
    if (e2 < best) { best = e2; bi = 4 * kb + 2; }
    if (e3 < best) { best = e3; bi = 4 * kb + 3; }
  }
  pred_g[row] = (unsigned char)bi;
  atomicAdd(&histS[bi], 1);

  float ssum = 0.f;
#pragma unroll
  for (int k = 0; k < KK; ++k) {
    const float e = __expf(BETA_C * (best - pv[k]));
    pv[k] = e;
    ssum += e;
  }
  const float inv = 1.0f / ssum;
#pragma unroll
  for (int k = 0; k < KK; ++k) pv[k] *= inv;

#pragma unroll
  for (int m = 32; m >= 1; m >>= 1) {
    const bool hi = (lane & m) != 0;
#pragma unroll
    for (int i = 0; i < m; ++i) {
      const float send = hi ? pv[i] : pv[i + m];
      const float recv = __shfl_xor(send, m, 64);
      const float keep = hi ? pv[i + m] : pv[i];
      pv[i] = keep + recv;
    }
  }
  fillW[wid][lane] = pv[0];
  __syncthreads();
  if (tid < KK) {
    atomicAdd(&fill_g[tid],
              fillW[0][tid] + fillW[1][tid] + fillW[2][tid] + fillW[3][tid]);
    if (histS[tid]) atomicAdd(&hist_g[tid], histS[tid]);
  }
}

// planner v2 (validated): 64 threads, wave-shuffle exclusive scans.
__global__ void planner_kernel(const int* __restrict__ hist_g,
                               int* __restrict__ segStart,
                               int* __restrict__ cursor,
                               unsigned char* __restrict__ wk,
                               int* __restrict__ wbase,
                               int* __restrict__ wcnt) {
  const int t = threadIdx.x;  // 64 threads, one wave
  const int c = hist_g[t];

  int inc = c;
#pragma unroll
  for (int off = 1; off < 64; off <<= 1) {
    const int v = __shfl_up(inc, off, 64);
    if (t >= off) inc += v;
  }
  const int seg = inc - c;  // exclusive
  segStart[t] = seg;
  cursor[t] = seg;
  if (t == 63) segStart[KK] = inc;  // == NR

  const int nw = (c + WROWS - 1) / WROWS;
  int winc = nw;
#pragma unroll
  for (int off = 1; off < 64; off <<= 1) {
    const int v = __shfl_up(winc, off, 64);
    if (t >= off) winc += v;
  }
  const int woff = winc - nw;
  const int wtot = __shfl(winc, 63, 64);  // total workers <= 576

  for (int wi = 0; wi < nw; ++wi) {
    wk[woff + wi] = (unsigned char)t;
    wbase[woff + wi] = seg + wi * WROWS;
    wcnt[woff + wi] = min(WROWS, c - wi * WROWS);
  }
  for (int w = wtot + t; w < GRIDW; w += 64) wk[w] = 255;
}

// scatter v2 (validated R11): counting-sort of ROW INDICES only.
__global__ __launch_bounds__(256) void scatter_kernel(
    const unsigned char* __restrict__ pred_g, int* __restrict__ cursor,
    unsigned int* __restrict__ idxg) {
  __shared__ int histS[KK];
  __shared__ int baseS[KK];

  const int tid = threadIdx.x;
  if (tid < KK) histS[tid] = 0;
  __syncthreads();

  const int row = blockIdx.x * 256 + tid;
  const int bi = pred_g[row];
  const int rank = atomicAdd(&histS[bi], 1);
  __syncthreads();
  if (tid < KK) {
    const int h = histS[tid];
    baseS[tid] = h ? atomicAdd(&cursor[tid], h) : 0;
  }
  __syncthreads();
  idxg[baseS[bi] + rank] = (unsigned int)row;  // ~4-row runs per cluster
}

// syrk v4 (validated R11): worker = (cluster k, <=256 rows via index list).
// Gather rows from x into transposed LDS tile; 4 wave-groups each compute a
// full 32x32 partial with 4x4 register tiles; LDS reduction across groups;
// lower-triangle atomic flush.
__global__ __launch_bounds__(256) void syrk_kernel(
    const float* __restrict__ x, const unsigned int* __restrict__ idxg,
    const unsigned char* __restrict__ wk, const int* __restrict__ wbase,
    const int* __restrict__ wcnt, float* __restrict__ m2low_g,
    float* __restrict__ sums_g) {
  __shared__ float xsT[DD][68];    // transposed tile, 8.7 KB (rows of 17 f4)
  __shared__ float red[4][64][16]; // per-group 4x4-tile partials, 16 KB
  __shared__ float sdred[4][DD];   // per-group row sums, 0.5 KB

  const int b = blockIdx.x;
  const int k = wk[b];
  if (k == 255) return;
  const int tid = threadIdx.x;
  const int base = wbase[b];
  const int total = wcnt[b];

  const int grp = tid >> 6;   // 4 groups == 4 waves
  const int t6 = tid & 63;
  const int ti = t6 >> 3;     // 0..7: output rows i = ti + 8r, r=0..3
  const int tj = t6 & 7;      // 0..7: output cols j = tj + 8c, c=0..3

  float cc[4][4];
#pragma unroll
  for (int r = 0; r < 4; ++r)
#pragma unroll
    for (int c2 = 0; c2 < 4; ++c2) cc[r][c2] = 0.f;
  float sd[4] = {0.f, 0.f, 0.f, 0.f};

  const float4* xf4 = (const float4*)x;
  const int rl0 = tid >> 3;       // row-local for pass 0 (0..31)
  const int pt = tid & 7;         // float4 slot within row

  for (int off = 0; off < total; off += 64) {
    const int cnt = min(64, total - off);
    const int cnt4 = (cnt + 3) & ~3;
    __syncthreads();  // previous tile's readers done before overwrite

    // gather <=64 rows from x via idx; lanes 0..7 share one row (bcast idx
    // load, 128 B coalesced row read as 2 float4 per thread-pass)
    if (rl0 < cnt) {
      const unsigned int r0 = idxg[base + off + rl0];
      const float4 v = xf4[(size_t)r0 * 8 + pt];
      xsT[pt * 4 + 0][rl0] = v.x;
      xsT[pt * 4 + 1][rl0] = v.y;
      xsT[pt * 4 + 2][rl0] = v.z;
      xsT[pt * 4 + 3][rl0] = v.w;
    }
    const int rl1 = rl0 + 32;
    if (rl1 < cnt) {
      const unsigned int r1 = idxg[base + off + rl1];
      const float4 v = xf4[(size_t)r1 * 8 + pt];
      xsT[pt * 4 + 0][rl1] = v.x;
      xsT[pt * 4 + 1][rl1] = v.y;
      xsT[pt * 4 + 2][rl1] = v.z;
      xsT[pt * 4 + 3][rl1] = v.w;
    }
    for (int e = cnt * DD + tid; e < cnt4 * DD; e += 256)
      xsT[e & 31][e >> 5] = 0.f;  // zero-pad rows to multiple of 4
    __syncthreads();

    const int gmax = cnt4 >> 2;
    for (int g = grp; g < gmax; g += 4) {  // row-quads strided by group
      float4 Af[4], Bf[4];
#pragma unroll
      for (int r = 0; r < 4; ++r)
        Af[r] = *(const float4*)&xsT[ti + 8 * r][4 * g];
#pragma unroll
      for (int c2 = 0; c2 < 4; ++c2)
        Bf[c2] = *(const float4*)&xsT[tj + 8 * c2][4 * g];
#pragma unroll
      for (int r = 0; r < 4; ++r)
#pragma unroll
        for (int c2 = 0; c2 < 4; ++c2)
          cc[r][c2] += Af[r].x * Bf[c2].x + Af[r].y * Bf[c2].y +
                       Af[r].z * Bf[c2].z + Af[r].w * Bf[c2].w;
      if (tj == 0) {
#pragma unroll
        for (int r = 0; r < 4; ++r)
          sd[r] += Af[r].x + Af[r].y + Af[r].z + Af[r].w;
      }
    }
  }

  // cross-group reduction through LDS, then triangular flush
#pragma unroll
  for (int r = 0; r < 4; ++r)
    *(float4*)&red[grp][t6][r * 4] =
        make_float4(cc[r][0], cc[r][1], cc[r][2], cc[r][3]);
  if (tj == 0) {
#pragma unroll
    for (int r = 0; r < 4; ++r) sdred[grp][ti + 8 * r] = sd[r];
  }
  __syncthreads();

  float* m2k = m2low_g + k * 528;
  {
    const int t6r = tid >> 2;        // which 4x4 tile (0..63)
    const int rr = tid & 3;          // which row of that tile
    const int tir = t6r >> 3, tjr = t6r & 7;
    const int i = tir + 8 * rr;
    float4 v0 = *(const float4*)&red[0][t6r][rr * 4];
    const float4 v1 = *(const float4*)&red[1][t6r][rr * 4];
    const float4 v2 = *(const float4*)&red[2][t6r][rr * 4];
    const float4 v3 = *(const float4*)&red[3][t6r][rr * 4];
    v0.x += v1.x + v2.x + v3.x;
    v0.y += v1.y + v2.y + v3.y;
    v0.z += v1.z + v2.z + v3.z;
    v0.w += v1.w + v2.w + v3.w;
    const float vv[4] = {v0.x, v0.y, v0.z, v0.w};
#pragma unroll
    for (int q = 0; q < 4; ++q) {
      const int j = tjr + 8 * q;
      if (j <= i) atomicAdd(&m2k[TRI(i, j)], vv[q]);
    }
  }
  if (tid < DD) {
    const float s =
        sdred[0][tid] + sdred[1][tid] + sdred[2][tid] + sdred[3][tid];
    atomicAdd(&sums_g[k * DD + tid], s);
  }
}

// finalize A (validated): one block per cluster.
__global__ __launch_bounds__(256) void finalizeA_kernel(
    const float* __restrict__ fill_g, const int* __restrict__ hist_g,
    const float* __restrict__ sums_g, const float* __restrict__ m2low_g,
    const float* __restrict__ ft, const float* __restrict__ mt,
    const float* __restrict__ ct, float* __restrict__ lossAcc) {
  __shared__ float meanS[DD];
  __shared__ float wred[4];
  const int t = threadIdx.x;
  const int k = blockIdx.x;

  const float inv = 1.0f / fmaxf((float)hist_g[k], 1.0f);
  if (t < DD) meanS[t] = sums_g[k * DD + t] * inv;
  __syncthreads();

  float acc = 0.f;
  if (t < DD) {
    const float d = meanS[t] - mt[k * DD + t];
    acc += d * d * (1.0f / (KK * DD));
  }
  if (t == 0) {
    const float f = fill_g[k] * (1.0f / (float)NR) - ft[k];
    acc += f * f * (1.0f / KK);
  }
  const float* m2k = m2low_g + k * 528;
  const float* ctk = ct + k * (DD * DD);
#pragma unroll
  for (int u = 0; u < 4; ++u) {
    const int e = t + 256 * u;
    const int i = e >> 5, j = e & 31;
    const int idx = (i >= j) ? TRI(i, j) : TRI(j, i);
    const float cov = m2k[idx] * inv - meanS[i] * meanS[j];
    const float d = cov - ctk[e];
    acc += d * d * (1.0f / (KK * DD * DD));
  }

  acc += __shfl_xor(acc, 32, 64);
  acc += __shfl_xor(acc, 16, 64);
  acc += __shfl_xor(acc, 8, 64);
  acc += __shfl_xor(acc, 4, 64);
  acc += __shfl_xor(acc, 2, 64);
  acc += __shfl_xor(acc, 1, 64);
  if ((t & 63) == 0) wred[t >> 6] = acc;
  __syncthreads();
  if (t == 0) atomicAdd(lossAcc, wred[0] + wred[1] + wred[2] + wred[3]);
}

__global__ void finalizeB_kernel(const float* __restrict__ lossAcc,
                                 float* __restrict__ out) {
  if (threadIdx.x == 0) out[0] = lossAcc[0];
}

extern "C" void kernel_launch(void* const* d_in, const int* in_sizes, int n_in,
                              void* d_out, int out_size, void* d_ws,
                              size_t ws_size, hipStream_t stream) {
  (void)in_sizes; (void)n_in; (void)out_size; (void)ws_size;
  const float* x = (const float*)d_in[0];
  const float* centers = (const float*)d_in[1];
  const float* ft = (const float*)d_in[2];
  const float* mt = (const float*)d_in[3];
  const float* ct = (const float*)d_in[4];
  float* out = (float*)d_out;

  float* ws = (float*)d_ws;
  float* fill_g = ws;                                   // 64
  float* lossAcc = ws + 64;                             // 1
  int* hist_g = (int*)(ws + 128);                       // 64
  int* segStart = (int*)(ws + 192);                     // 65
  int* cursor = (int*)(ws + 320);                       // 64
  unsigned char* wk = (unsigned char*)(ws + 384);       // GRIDW bytes
  int* wbase = (int*)(ws + 544);                        // GRIDW
  int* wcnt = (int*)(ws + 1184);                        // GRIDW
  float* m2low_g = ws + 1824;                           // 33792
  float* sums_g = ws + 35616;                           // 2048
  unsigned char* pred8 = (unsigned char*)(ws + 37664);  // N bytes
  unsigned int* idxg = (unsigned int*)(ws + 70432);     // N uints (512 KB)

  hipMemsetAsync(d_ws, 0, (size_t)37664 * sizeof(float), stream);

  phase1_kernel<<<NR / 256, 256, 0, stream>>>(x, centers, fill_g, hist_g,
                                              pred8);
  planner_kernel<<<1, 64, 0, stream>>>(hist_g, segStart, cursor, wk, wbase,
                                       wcnt);
  scatter_kernel<<<NR / 256, 256, 0, stream>>>(pred8, cursor, idxg);
  syrk_kernel<<<GRIDW, 256, 0, stream>>>(x, idxg, wk, wbase, wcnt, m2low_g,
                                         sums_g);
  finalizeA_kernel<<<KK, 256, 0, stream>>>(fill_g, hist_g, sums_g, m2low_g, ft,
                                           mt, ct, lossAcc);
  finalizeB_kernel<<<1, 64, 0, stream>>>(lossAcc, out);
}

// Round 8
// 129.406 us; speedup vs baseline: 1.1039x; 1.0326x over previous
//
#include <hip/hip_runtime.h>

#define NR 131072
#define DD 32
#define KK 64
#define BETA_C 10.0f
#define WROWS 256                    // rows per syrk worker
#define GRIDW 640                    // >= sum ceil(c_k/WROWS) <= 512+64 = 576
#define TRI(i, j) ((i) * ((i) + 1) / 2 + (j))

// ---------------------------------------------------------------------------
// R15 = R12 + dispatch-count reduction 7 -> 5, fence-free on hot paths:
//   (1) planner removed: scatter re-derives the hist scan in-block (cursor is
//       zero-based; baseS = seg + atomicAdd(cursor,h) == validated values);
//       syrk wave0 scans hist, locates its worker interval, broadcasts
//       (k, base, cnt) via LDS. Redundant 64-int scans are ~free.
//   (2) finalizeB fused into finalizeA per the R8-validated last-block
//       pattern (fence only at pipeline END, nothing runs after).
//   (3) memset shrunk to 1.5 KB; m2low/sums zeroed inside scatter
//       (R8-validated, stream-ordered ahead of syrk's atomics).
//
// ws layout (float-indexed):
//   [0,64)   fill_g   [64,65) lossAcc   [67,68) doneF(int)
//   [128,192) hist_g (int)   [320,384) cursor (int)
//   [1824,35616) m2low_g (K x 528 tri)  [35616,37664) sums_g (K x 32)
//   [37664,70432) pred8 (uchar N)       [70432,+N) idx (uint N, 512 KB)
// memset zeroes [0,384) floats only; m2low/sums zeroed by scatter.
// ---------------------------------------------------------------------------

// phase 1 (R12 verbatim, measured-best): one row/thread, centers via
// wave-uniform s_load path, 63-shuffle transpose-reduce, block histogram.
__global__ __launch_bounds__(256, 2) void phase1_kernel(
    const float* __restrict__ x, const float* __restrict__ centers,
    float* __restrict__ fill_g, int* __restrict__ hist_g,
    unsigned char* __restrict__ pred_g) {
  __shared__ float cnS[KK];
  __shared__ float fillW[4][KK];
  __shared__ int histS[KK];

  const int tid = threadIdx.x;
  const int lane = tid & 63;
  const int wid = tid >> 6;

  if (tid < KK) {
    float s = 0.f;
    const float* cp = centers + tid * DD;
#pragma unroll
    for (int j = 0; j < DD; ++j) s += cp[j] * cp[j];
    cnS[tid] = s;
    histS[tid] = 0;
  }
  __syncthreads();

  const int row = blockIdx.x * 256 + tid;  // grid == NR/256 exactly

  float xr[DD];
  const float4* xp = (const float4*)(x + (size_t)row * DD);
#pragma unroll
  for (int j = 0; j < 8; ++j) {
    const float4 v = xp[j];
    xr[4 * j + 0] = v.x;
    xr[4 * j + 1] = v.y;
    xr[4 * j + 2] = v.z;
    xr[4 * j + 3] = v.w;
  }
  float xx = 0.f;
#pragma unroll
  for (int j = 0; j < DD; ++j) xx += xr[j] * xr[j];

  float pv[KK];
  float best = 3.4e38f;
  int bi = 0;
#pragma unroll
  for (int k = 0; k < KK; ++k) {
    float dot = 0.f;
#pragma unroll
    for (int j = 0; j < DD; ++j)
      dot += xr[j] * centers[k * DD + j];  // uniform addr -> s_load (K$)
    const float d2 = xx - 2.0f * dot + cnS[k];
    pv[k] = d2;
    if (d2 < best) { best = d2; bi = k; }  // strict < == first-index ties
  }
  pred_g[row] = (unsigned char)bi;
  atomicAdd(&histS[bi], 1);

  float ssum = 0.f;
#pragma unroll
  for (int k = 0; k < KK; ++k) {
    const float e = __expf(BETA_C * (best - pv[k]));
    pv[k] = e;
    ssum += e;
  }
  const float inv = 1.0f / ssum;
#pragma unroll
  for (int k = 0; k < KK; ++k) pv[k] *= inv;

#pragma unroll
  for (int m = 32; m >= 1; m >>= 1) {
    const bool hi = (lane & m) != 0;
#pragma unroll
    for (int i = 0; i < m; ++i) {
      const float send = hi ? pv[i] : pv[i + m];
      const float recv = __shfl_xor(send, m, 64);
      const float keep = hi ? pv[i + m] : pv[i];
      pv[i] = keep + recv;
    }
  }
  fillW[wid][lane] = pv[0];
  __syncthreads();
  if (tid < KK) {
    atomicAdd(&fill_g[tid],
              fillW[0][tid] + fillW[1][tid] + fillW[2][tid] + fillW[3][tid]);
    if (histS[tid]) atomicAdd(&hist_g[tid], histS[tid]);
  }
}

// scatter v3: counting-sort of ROW INDICES; self-plans the cluster segment
// bases via an in-block scan of hist_g (cursor zero-based -> values identical
// to the validated planner path). Also zeroes m2low_g+sums_g (8960 float4
// across 512 blocks; stream-ordered ahead of syrk's atomics).
__global__ __launch_bounds__(256) void scatter_kernel(
    const unsigned char* __restrict__ pred_g, const int* __restrict__ hist_g,
    int* __restrict__ cursor, unsigned int* __restrict__ idxg,
    float4* __restrict__ m2zero) {
  __shared__ int histS[KK];
  __shared__ int baseS[KK];

  const int tid = threadIdx.x;
  if (tid < 18) {  // zero m2low_g + sums_g: 35840 floats = 8960 float4
    const int z = blockIdx.x * 18 + tid;
    if (z < 8960) m2zero[z] = make_float4(0.f, 0.f, 0.f, 0.f);
  }
  if (tid < KK) histS[tid] = 0;
  __syncthreads();

  const int row = blockIdx.x * 256 + tid;
  const int bi = pred_g[row];
  const int rank = atomicAdd(&histS[bi], 1);
  __syncthreads();
  if (tid < KK) {  // threads 0..63 == wave 0: shuffle-scan is safe
    const int c = hist_g[tid];
    int inc = c;
#pragma unroll
    for (int off = 1; off < 64; off <<= 1) {
      const int v = __shfl_up(inc, off, 64);
      if (tid >= off) inc += v;
    }
    const int seg = inc - c;  // exclusive scan == segStart[tid]
    const int h = histS[tid];
    baseS[tid] = seg + (h ? atomicAdd(&cursor[tid], h) : 0);
  }
  __syncthreads();
  idxg[baseS[bi] + rank] = (unsigned int)row;  // ~4-row runs per cluster
}

// syrk v5: self-planning worker = (cluster k, <=256 rows via index list).
// Wave 0 scans hist_g, finds the worker interval containing blockIdx, and
// broadcasts (k, base, cnt). Compute core = validated R11 syrk v4.
__global__ __launch_bounds__(256) void syrk_kernel(
    const float* __restrict__ x, const unsigned int* __restrict__ idxg,
    const int* __restrict__ hist_g, float* __restrict__ m2low_g,
    float* __restrict__ sums_g) {
  __shared__ float xsT[DD][68];    // transposed tile, 8.7 KB (rows of 17 f4)
  __shared__ float red[4][64][16]; // per-group 4x4-tile partials, 16 KB
  __shared__ float sdred[4][DD];   // per-group row sums, 0.5 KB
  __shared__ int planS[3];         // k, base, cnt

  const int tid = threadIdx.x;
  if (tid < 64) {  // wave 0: derive this block's worker assignment
    const int c = hist_g[tid];
    int inc = c;
#pragma unroll
    for (int off = 1; off < 64; off <<= 1) {
      const int v = __shfl_up(inc, off, 64);
      if (tid >= off) inc += v;
    }
    const int seg = inc - c;
    const int nw = (c + WROWS - 1) / WROWS;
    int winc = nw;
#pragma unroll
    for (int off = 1; off < 64; off <<= 1) {
      const int v = __shfl_up(winc, off, 64);
      if (tid >= off) winc += v;
    }
    const int woff = winc - nw;
    const int wtot = __shfl(winc, 63, 64);  // total workers <= 576
    const int b = blockIdx.x;
    if (b >= wtot) {
      if (tid == 0) planS[0] = 255;
    } else if (b >= woff && b < woff + nw) {  // exactly one lane
      const int wi = b - woff;
      planS[0] = tid;
      planS[1] = seg + wi * WROWS;
      planS[2] = min(WROWS, c - wi * WROWS);
    }
  }
  __syncthreads();
  const int k = planS[0];
  if (k == 255) return;  // uniform exit after barrier
  const int base = planS[1];
  const int total = planS[2];

  const int grp = tid >> 6;   // 4 groups == 4 waves
  const int t6 = tid & 63;
  const int ti = t6 >> 3;     // 0..7: output rows i = ti + 8r, r=0..3
  const int tj = t6 & 7;      // 0..7: output cols j = tj + 8c, c=0..3

  float cc[4][4];
#pragma unroll
  for (int r = 0; r < 4; ++r)
#pragma unroll
    for (int c2 = 0; c2 < 4; ++c2) cc[r][c2] = 0.f;
  float sd[4] = {0.f, 0.f, 0.f, 0.f};

  const float4* xf4 = (const float4*)x;
  const int rl0 = tid >> 3;       // row-local for pass 0 (0..31)
  const int pt = tid & 7;         // float4 slot within row

  for (int off = 0; off < total; off += 64) {
    const int cnt = min(64, total - off);
    const int cnt4 = (cnt + 3) & ~3;
    __syncthreads();  // previous tile's readers done before overwrite

    if (rl0 < cnt) {
      const unsigned int r0 = idxg[base + off + rl0];
      const float4 v = xf4[(size_t)r0 * 8 + pt];
      xsT[pt * 4 + 0][rl0] = v.x;
      xsT[pt * 4 + 1][rl0] = v.y;
      xsT[pt * 4 + 2][rl0] = v.z;
      xsT[pt * 4 + 3][rl0] = v.w;
    }
    const int rl1 = rl0 + 32;
    if (rl1 < cnt) {
      const unsigned int r1 = idxg[base + off + rl1];
      const float4 v = xf4[(size_t)r1 * 8 + pt];
      xsT[pt * 4 + 0][rl1] = v.x;
      xsT[pt * 4 + 1][rl1] = v.y;
      xsT[pt * 4 + 2][rl1] = v.z;
      xsT[pt * 4 + 3][rl1] = v.w;
    }
    for (int e = cnt * DD + tid; e < cnt4 * DD; e += 256)
      xsT[e & 31][e >> 5] = 0.f;  // zero-pad rows to multiple of 4
    __syncthreads();

    const int gmax = cnt4 >> 2;
    for (int g = grp; g < gmax; g += 4) {  // row-quads strided by group
      float4 Af[4], Bf[4];
#pragma unroll
      for (int r = 0; r < 4; ++r)
        Af[r] = *(const float4*)&xsT[ti + 8 * r][4 * g];
#pragma unroll
      for (int c2 = 0; c2 < 4; ++c2)
        Bf[c2] = *(const float4*)&xsT[tj + 8 * c2][4 * g];
#pragma unroll
      for (int r = 0; r < 4; ++r)
#pragma unroll
        for (int c2 = 0; c2 < 4; ++c2)
          cc[r][c2] += Af[r].x * Bf[c2].x + Af[r].y * Bf[c2].y +
                       Af[r].z * Bf[c2].z + Af[r].w * Bf[c2].w;
      if (tj == 0) {
#pragma unroll
        for (int r = 0; r < 4; ++r)
          sd[r] += Af[r].x + Af[r].y + Af[r].z + Af[r].w;
      }
    }
  }

  // cross-group reduction through LDS, then triangular flush
#pragma unroll
  for (int r = 0; r < 4; ++r)
    *(float4*)&red[grp][t6][r * 4] =
        make_float4(cc[r][0], cc[r][1], cc[r][2], cc[r][3]);
  if (tj == 0) {
#pragma unroll
    for (int r = 0; r < 4; ++r) sdred[grp][ti + 8 * r] = sd[r];
  }
  __syncthreads();

  float* m2k = m2low_g + k * 528;
  {
    const int t6r = tid >> 2;        // which 4x4 tile (0..63)
    const int rr = tid & 3;          // which row of that tile
    const int tir = t6r >> 3, tjr = t6r & 7;
    const int i = tir + 8 * rr;
    float4 v0 = *(const float4*)&red[0][t6r][rr * 4];
    const float4 v1 = *(const float4*)&red[1][t6r][rr * 4];
    const float4 v2 = *(const float4*)&red[2][t6r][rr * 4];
    const float4 v3 = *(const float4*)&red[3][t6r][rr * 4];
    v0.x += v1.x + v2.x + v3.x;
    v0.y += v1.y + v2.y + v3.y;
    v0.z += v1.z + v2.z + v3.z;
    v0.w += v1.w + v2.w + v3.w;
    const float vv[4] = {v0.x, v0.y, v0.z, v0.w};
#pragma unroll
    for (int q = 0; q < 4; ++q) {
      const int j = tjr + 8 * q;
      if (j <= i) atomicAdd(&m2k[TRI(i, j)], vv[q]);
    }
  }
  if (tid < DD) {
    const float s =
        sdred[0][tid] + sdred[1][tid] + sdred[2][tid] + sdred[3][tid];
    atomicAdd(&sums_g[k * DD + tid], s);
  }
}

// finalize (R8-validated fused form): one block per cluster; last-arriving
// block writes the output scalar. Fence sits at pipeline END (nothing runs
// after), so its L2 writeback cannot hurt any later consumer.
__global__ __launch_bounds__(256) void finalize_kernel(
    const float* __restrict__ fill_g, const int* __restrict__ hist_g,
    const float* __restrict__ sums_g, const float* __restrict__ m2low_g,
    const float* __restrict__ ft, const float* __restrict__ mt,
    const float* __restrict__ ct, float* __restrict__ lossAcc,
    int* __restrict__ doneF, float* __restrict__ out) {
  __shared__ float meanS[DD];
  __shared__ float wred[4];
  const int t = threadIdx.x;
  const int k = blockIdx.x;

  const float inv = 1.0f / fmaxf((float)hist_g[k], 1.0f);
  if (t < DD) meanS[t] = sums_g[k * DD + t] * inv;
  __syncthreads();

  float acc = 0.f;
  if (t < DD) {
    const float d = meanS[t] - mt[k * DD + t];
    acc += d * d * (1.0f / (KK * DD));
  }
  if (t == 0) {
    const float f = fill_g[k] * (1.0f / (float)NR) - ft[k];
    acc += f * f * (1.0f / KK);
  }
  const float* m2k = m2low_g + k * 528;
  const float* ctk = ct + k * (DD * DD);
#pragma unroll
  for (int u = 0; u < 4; ++u) {
    const int e = t + 256 * u;
    const int i = e >> 5, j = e & 31;
    const int idx = (i >= j) ? TRI(i, j) : TRI(j, i);
    const float cov = m2k[idx] * inv - meanS[i] * meanS[j];
    const float d = cov - ctk[e];
    acc += d * d * (1.0f / (KK * DD * DD));
  }

  acc += __shfl_xor(acc, 32, 64);
  acc += __shfl_xor(acc, 16, 64);
  acc += __shfl_xor(acc, 8, 64);
  acc += __shfl_xor(acc, 4, 64);
  acc += __shfl_xor(acc, 2, 64);
  acc += __shfl_xor(acc, 1, 64);
  if ((t & 63) == 0) wred[t >> 6] = acc;
  __syncthreads();
  if (t == 0) {
    atomicAdd(lossAcc, wred[0] + wred[1] + wred[2] + wred[3]);
    __threadfence();  // release: lossAcc visible before doneF bump
    if (atomicAdd(doneF, 1) == KK - 1) {
      out[0] = atomicAdd(lossAcc, 0.0f);  // coherent-path read
    }
  }
}

extern "C" void kernel_launch(void* const* d_in, const int* in_sizes, int n_in,
                              void* d_out, int out_size, void* d_ws,
                              size_t ws_size, hipStream_t stream) {
  (void)in_sizes; (void)n_in; (void)out_size; (void)ws_size;
  const float* x = (const float*)d_in[0];
  const float* centers = (const float*)d_in[1];
  const float* ft = (const float*)d_in[2];
  const float* mt = (const float*)d_in[3];
  const float* ct = (const float*)d_in[4];
  float* out = (float*)d_out;

  float* ws = (float*)d_ws;
  float* fill_g = ws;                                   // 64
  float* lossAcc = ws + 64;                             // 1
  int* doneF = (int*)(ws + 67);                         // 1
  int* hist_g = (int*)(ws + 128);                       // 64
  int* cursor = (int*)(ws + 320);                       // 64
  float* m2low_g = ws + 1824;                           // 33792
  float* sums_g = ws + 35616;                           // 2048
  unsigned char* pred8 = (unsigned char*)(ws + 37664);  // N bytes
  unsigned int* idxg = (unsigned int*)(ws + 70432);     // N uints (512 KB)

  // zero fill_g/lossAcc/doneF/hist/cursor only (1.5 KB); m2low/sums are
  // zeroed inside scatter (stream-ordered ahead of syrk's atomics).
  hipMemsetAsync(d_ws, 0, (size_t)384 * sizeof(float), stream);

  phase1_kernel<<<NR / 256, 256, 0, stream>>>(x, centers, fill_g, hist_g,
                                              pred8);
  scatter_kernel<<<NR / 256, 256, 0, stream>>>(pred8, hist_g, cursor, idxg,
                                               (float4*)m2low_g);
  syrk_kernel<<<GRIDW, 256, 0, stream>>>(x, idxg, hist_g, m2low_g, sums_g);
  finalize_kernel<<<KK, 256, 0, stream>>>(fill_g, hist_g, sums_g, m2low_g, ft,
                                          mt, ct, lossAcc, doneF, out);
}